// Round 1
// baseline (3339.665 us; speedup 1.0000x reference)
//
#include <hip/hip_runtime.h>
#include <hip/hip_bf16.h>
#include <math.h>

#define B_ 4
#define T_ 2048
#define D_ 1024
#define H_ 16
#define HD_ 64

// ---------------------------------------------------------------------------
// GEMM: C[M,N] = A[M,K] @ W[N,K]^T   (fp32, M=B*T or 8192, N=K=D=1024)
// 64x64 tile, 256 threads, 4x4 per thread, BK=16, LDS padded +1.
// ---------------------------------------------------------------------------
__global__ __launch_bounds__(256) void gemm_bt(const float* __restrict__ A,
                                               const float* __restrict__ W,
                                               float* __restrict__ C) {
    const int K = D_;
    __shared__ float As[16][65];
    __shared__ float Bs[16][65];
    const int tid = threadIdx.x;
    const int tx = tid & 15, ty = tid >> 4;
    const int row0 = blockIdx.y * 64, col0 = blockIdx.x * 64;
    float acc[4][4] = {};
    for (int kt = 0; kt < K / 16; ++kt) {
        const int kbase = kt * 16;
#pragma unroll
        for (int i = 0; i < 4; ++i) {
            const int r = ty + i * 16;
            As[tx][r] = A[(size_t)(row0 + r) * K + kbase + tx];
            Bs[tx][r] = W[(size_t)(col0 + r) * K + kbase + tx];
        }
        __syncthreads();
#pragma unroll
        for (int kk = 0; kk < 16; ++kk) {
            float a[4], b[4];
#pragma unroll
            for (int i = 0; i < 4; ++i) a[i] = As[kk][ty * 4 + i];
#pragma unroll
            for (int j = 0; j < 4; ++j) b[j] = Bs[kk][tx * 4 + j];
#pragma unroll
            for (int i = 0; i < 4; ++i)
#pragma unroll
                for (int j = 0; j < 4; ++j)
                    acc[i][j] = fmaf(a[i], b[j], acc[i][j]);
        }
        __syncthreads();
    }
#pragma unroll
    for (int i = 0; i < 4; ++i)
#pragma unroll
        for (int j = 0; j < 4; ++j)
            C[(size_t)(row0 + ty * 4 + i) * D_ + col0 + tx * 4 + j] = acc[i][j];
}

// ---------------------------------------------------------------------------
// Fused RMSNorm (over HD=64) + rotary. One wave (64 threads) per (b,t,h) row.
// grid.x = B*T*H, grid.y = 2 (0 -> q, 1 -> k). lane = dim index.
// rotary: n=16 real freqs f_j = (1/1024)^(j/15) = 2^(-10j/15), j in [0,16);
// f_j = 0 for j in [16,32). x1 = dims [0,32), x2 = dims [32,64).
// y1 = x1*c + x2*s ; y2 = -x1*s + x2*c.
// ---------------------------------------------------------------------------
__global__ __launch_bounds__(64) void rmsrot(float* __restrict__ q,
                                             float* __restrict__ k) {
    const int lane = threadIdx.x;
    const long long idx = blockIdx.x;          // (b*T + t)*H + h
    const int h = (int)(idx % H_);
    const long long bt = idx / H_;
    const int t = (int)(bt % T_);
    float* p = (blockIdx.y == 0 ? q : k) + bt * (long long)D_ + h * HD_ + lane;
    float v = *p;
    float ss = v * v;
#pragma unroll
    for (int o = 32; o > 0; o >>= 1) ss += __shfl_xor(ss, o, 64);
    v *= rsqrtf(ss * (1.0f / 64.0f) + 1e-6f);
    const int j = lane & 31;
    const float f = (j < 16) ? exp2f(-10.0f * (float)j * (1.0f / 15.0f)) : 0.0f;
    const float theta = (float)t * f;
    float s, c;
    sincosf(theta, &s, &c);
    const float partner = __shfl_xor(v, 32, 64);
    // lane<32: v is x1, partner is x2 ; lane>=32: partner is x1, v is x2
    const float y = (lane < 32) ? fmaf(v, c, partner * s)
                                : fmaf(v, c, -partner * s);
    *p = y;
}

// ---------------------------------------------------------------------------
// Causal flash attention, fp32. One thread per query row, 128 queries/block.
// Online softmax in exp2 domain (q pre-scaled by 0.125*log2(e)).
// grid = (T/128, H, B). Writes O in-place over the Q buffer (safe: each
// (b,t,h) row is read only by its owning thread, which reads before writing).
// ---------------------------------------------------------------------------
#define QT 128
#define KT 32

__global__ __launch_bounds__(128) void flash(const float* __restrict__ q,
                                             const float* __restrict__ k,
                                             const float* __restrict__ v,
                                             float* __restrict__ o) {
    __shared__ float Ks[KT][HD_];
    __shared__ float Vs[KT][HD_];
    const int tid = threadIdx.x;
    const int qidx = blockIdx.x * QT + tid;
    const int h = blockIdx.y, b = blockIdx.z;
    const float scale = 0.125f * 1.44269504088896340736f;  // /sqrt(64) * log2(e)
    const size_t qoff = ((size_t)(b * T_ + qidx) * H_ + h) * HD_;
    float qr[HD_];
#pragma unroll
    for (int d = 0; d < HD_; ++d) qr[d] = q[qoff + d] * scale;
    float oacc[HD_] = {};
    float m = -3.0e38f, l = 0.0f;
    const int nkt = (blockIdx.x * QT + QT) / KT;
    for (int kt = 0; kt < nkt; ++kt) {
        const int k0 = kt * KT;
#pragma unroll
        for (int i = 0; i < (KT * HD_) / 128; ++i) {
            const int fidx = i * 128 + tid;
            const int r = fidx >> 6, c = fidx & 63;
            const size_t g = ((size_t)(b * T_ + k0 + r) * H_ + h) * HD_ + c;
            Ks[r][c] = k[g];
            Vs[r][c] = v[g];
        }
        __syncthreads();
        float s[KT];
        float tmax = -3.0e38f;
        const bool need_mask = (k0 + KT - 1) > qidx;
#pragma unroll
        for (int kk = 0; kk < KT; ++kk) {
            float acc = 0.f;
#pragma unroll
            for (int d = 0; d < HD_; ++d) acc = fmaf(qr[d], Ks[kk][d], acc);
            if (need_mask && (k0 + kk) > qidx) acc = -3.0e38f;
            s[kk] = acc;
            tmax = fmaxf(tmax, acc);
        }
        const float mnew = fmaxf(m, tmax);
        const float corr = exp2f(m - mnew);
        m = mnew;
        l *= corr;
#pragma unroll
        for (int d = 0; d < HD_; ++d) oacc[d] *= corr;
#pragma unroll
        for (int kk = 0; kk < KT; ++kk) {
            const float p = exp2f(s[kk] - m);
            l += p;
#pragma unroll
            for (int d = 0; d < HD_; ++d) oacc[d] = fmaf(p, Vs[kk][d], oacc[d]);
        }
        __syncthreads();
    }
    const float inv = 1.0f / l;
#pragma unroll
    for (int d = 0; d < HD_; ++d) o[qoff + d] = oacc[d] * inv;
}

// ---------------------------------------------------------------------------
extern "C" void kernel_launch(void* const* d_in, const int* in_sizes, int n_in,
                              void* d_out, int out_size, void* d_ws, size_t ws_size,
                              hipStream_t stream) {
    const float* x  = (const float*)d_in[0];
    const float* wq = (const float*)d_in[1];
    const float* wk = (const float*)d_in[2];
    const float* wv = (const float*)d_in[3];
    const float* wo = (const float*)d_in[4];
    // d_in[5] = mask (tril) — causality is hard-coded in the flash kernel.
    float* out = (float*)d_out;

    const size_t NELEM = (size_t)B_ * T_ * D_;  // 8,388,608
    float* qb = (float*)d_ws;
    float* kb = qb + NELEM;
    float* vb = kb + NELEM;

    dim3 gemm_grid(D_ / 64, (B_ * T_) / 64, 1);  // (16, 128)
    gemm_bt<<<gemm_grid, 256, 0, stream>>>(x, wq, qb);
    gemm_bt<<<gemm_grid, 256, 0, stream>>>(x, wk, kb);
    gemm_bt<<<gemm_grid, 256, 0, stream>>>(x, wv, vb);

    rmsrot<<<dim3(B_ * T_ * H_, 2), 64, 0, stream>>>(qb, kb);

    flash<<<dim3(T_ / QT, H_, B_), 128, 0, stream>>>(qb, kb, vb, qb);

    gemm_bt<<<gemm_grid, 256, 0, stream>>>(qb, wo, out);
}

// Round 2
// 1756.787 us; speedup vs baseline: 1.9010x; 1.9010x over previous
//
#include <hip/hip_runtime.h>
#include <hip/hip_bf16.h>
#include <math.h>

#define B_ 4
#define T_ 2048
#define D_ 1024
#define H_ 16
#define HD_ 64

typedef unsigned short ushort_t;
typedef _Float16 f16x8 __attribute__((ext_vector_type(8)));
typedef float f32x4 __attribute__((ext_vector_type(4)));

// ---------------------------------------------------------------------------
// GEMM: C[M,N] = A[M,K] @ W[N,K]^T   (fp32) — unchanged from round 1.
// ---------------------------------------------------------------------------
__global__ __launch_bounds__(256) void gemm_bt(const float* __restrict__ A,
                                               const float* __restrict__ W,
                                               float* __restrict__ C) {
    const int K = D_;
    __shared__ float As[16][65];
    __shared__ float Bs[16][65];
    const int tid = threadIdx.x;
    const int tx = tid & 15, ty = tid >> 4;
    const int row0 = blockIdx.y * 64, col0 = blockIdx.x * 64;
    float acc[4][4] = {};
    for (int kt = 0; kt < K / 16; ++kt) {
        const int kbase = kt * 16;
#pragma unroll
        for (int i = 0; i < 4; ++i) {
            const int r = ty + i * 16;
            As[tx][r] = A[(size_t)(row0 + r) * K + kbase + tx];
            Bs[tx][r] = W[(size_t)(col0 + r) * K + kbase + tx];
        }
        __syncthreads();
#pragma unroll
        for (int kk = 0; kk < 16; ++kk) {
            float a[4], b[4];
#pragma unroll
            for (int i = 0; i < 4; ++i) a[i] = As[kk][ty * 4 + i];
#pragma unroll
            for (int j = 0; j < 4; ++j) b[j] = Bs[kk][tx * 4 + j];
#pragma unroll
            for (int i = 0; i < 4; ++i)
#pragma unroll
                for (int j = 0; j < 4; ++j)
                    acc[i][j] = fmaf(a[i], b[j], acc[i][j]);
        }
        __syncthreads();
    }
#pragma unroll
    for (int i = 0; i < 4; ++i)
#pragma unroll
        for (int j = 0; j < 4; ++j)
            C[(size_t)(row0 + ty * 4 + i) * D_ + col0 + tx * 4 + j] = acc[i][j];
}

// ---------------------------------------------------------------------------
// Fused RMSNorm + rotary; reads fp32 q/k, writes fp16 q/k.
// Q is pre-scaled by 1/sqrt(HD) * log2(e) so flash can use exp2 directly.
// ---------------------------------------------------------------------------
__global__ __launch_bounds__(64) void rmsrot(const float* __restrict__ qf,
                                             const float* __restrict__ kf,
                                             _Float16* __restrict__ qh,
                                             _Float16* __restrict__ kh) {
    const int lane = threadIdx.x;
    const long long idx = blockIdx.x;          // (b*T + t)*H + h
    const int h = (int)(idx % H_);
    const long long bt = idx / H_;
    const int t = (int)(bt % T_);
    const long long off = bt * (long long)D_ + h * HD_ + lane;
    const float* src = (blockIdx.y == 0 ? qf : kf);
    float v = src[off];
    float ss = v * v;
#pragma unroll
    for (int o = 32; o > 0; o >>= 1) ss += __shfl_xor(ss, o, 64);
    v *= rsqrtf(ss * (1.0f / 64.0f) + 1e-6f);
    const int j = lane & 31;
    const float f = (j < 16) ? exp2f(-10.0f * (float)j * (1.0f / 15.0f)) : 0.0f;
    const float theta = (float)t * f;
    float s, c;
    sincosf(theta, &s, &c);
    const float partner = __shfl_xor(v, 32, 64);
    const float y = (lane < 32) ? fmaf(v, c, partner * s)
                                : fmaf(v, c, -partner * s);
    if (blockIdx.y == 0)
        qh[off] = (_Float16)(y * 0.18033688011112042f);  // 0.125*log2(e)
    else
        kh[off] = (_Float16)y;
}

// ---------------------------------------------------------------------------
// V prep: fp32 V[b][t][h][d]  ->  fp16 Vt[b][h][d][T]  (cast + transpose).
// One block per (64-t tile, h, b). 256 threads.
// ---------------------------------------------------------------------------
__global__ __launch_bounds__(256) void vtprep(const float* __restrict__ vf,
                                              _Float16* __restrict__ vt) {
    __shared__ _Float16 Tl[64 * 80];
    const int tid = threadIdx.x;
    const int t0 = blockIdx.x * 64, h = blockIdx.y, b = blockIdx.z;
#pragma unroll
    for (int rep = 0; rep < 4; ++rep) {
        const int idx = rep * 256 + tid;       // 0..1023
        const int i = idx >> 4, c = idx & 15;  // t-row i, d-chunk c
        const float4 v4 = *(const float4*)(vf + ((size_t)(b * T_ + t0 + i) * H_ + h) * HD_ + c * 4);
        Tl[(c * 4 + 0) * 80 + i] = (_Float16)v4.x;
        Tl[(c * 4 + 1) * 80 + i] = (_Float16)v4.y;
        Tl[(c * 4 + 2) * 80 + i] = (_Float16)v4.z;
        Tl[(c * 4 + 3) * 80 + i] = (_Float16)v4.w;
    }
    __syncthreads();
    const int d = tid >> 2, tc = (tid & 3) * 16;
    const uint4 a = *(const uint4*)&Tl[d * 80 + tc];
    const uint4 b4 = *(const uint4*)&Tl[d * 80 + tc + 8];
    _Float16* dst = vt + ((size_t)(b * H_ + h) * HD_ + d) * T_ + t0 + tc;
    *(uint4*)(dst) = a;
    *(uint4*)(dst + 8) = b4;
}

// ---------------------------------------------------------------------------
// MFMA flash attention (fp16 in, fp32 out). Block: 64 queries, 4 waves.
// Wave w owns q rows [q0+16w, q0+16w+16). K-tiles of 64 keys.
// S = Q@K^T via mfma_f32_16x16x32_f16 (A=Q frag in regs, B=K from LDS,
// natural [key][d] layout). P -> LDS round-trip -> A-operand for PV with
// B=Vt from LDS ([d][key] layout). All LDS rows padded to 88 elems
// (176 B: 16B-aligned for ds_read_b128, bank stride 12 -> <=2-way).
// ---------------------------------------------------------------------------
#define LDK 88
#define LDP 88

__global__ __launch_bounds__(256) void flash_mfma(const _Float16* __restrict__ qh,
                                                  const _Float16* __restrict__ kh,
                                                  const _Float16* __restrict__ vt,
                                                  float* __restrict__ o) {
    __shared__ _Float16 Kl[64 * LDK];
    __shared__ _Float16 Vl[64 * LDK];
    __shared__ _Float16 Pl[4][16 * LDP];
    const int tid = threadIdx.x;
    const int lane = tid & 63, w = tid >> 6;
    const int col = lane & 15, quad = lane >> 4;
    const int q0 = blockIdx.x * 64;
    const int h = blockIdx.y, b = blockIdx.z;

    // Q A-frags: lane holds Q[q = q0+16w+col][d = quad*8 + j (+32)]
    const int tq = q0 + w * 16 + col;
    const _Float16* qp = qh + ((size_t)(b * T_ + tq) * H_ + h) * HD_ + quad * 8;
    const f16x8 qA0 = *(const f16x8*)(qp);
    const f16x8 qA1 = *(const f16x8*)(qp + 32);

    f32x4 oa[4];
#pragma unroll
    for (int i = 0; i < 4; ++i) oa[i] = (f32x4){0.f, 0.f, 0.f, 0.f};
    float m_[4] = {-1e30f, -1e30f, -1e30f, -1e30f};
    float l_[4] = {0.f, 0.f, 0.f, 0.f};

    const int nkt = blockIdx.x + 1;  // K-tiles of 64, causal
    for (int kt = 0; kt < nkt; ++kt) {
        const int k0 = kt * 64;
        // ---- stage K tile [64 keys][64 d] and Vt tile [64 d][64 keys] ----
#pragma unroll
        for (int rep = 0; rep < 2; ++rep) {
            const int idx = rep * 256 + tid;   // 0..511
            const int row = idx >> 3, ch = idx & 7;
            const uint4 kv = *(const uint4*)(kh + ((size_t)(b * T_ + k0 + row) * H_ + h) * HD_ + ch * 8);
            *(uint4*)&Kl[row * LDK + ch * 8] = kv;
            const uint4 vv = *(const uint4*)(vt + ((size_t)(b * H_ + h) * HD_ + row) * T_ + k0 + ch * 8);
            *(uint4*)&Vl[row * LDK + ch * 8] = vv;
        }
        __syncthreads();

        // ---- S[16 q][64 key] = Q @ K^T : 4 n-tiles x 2 k-chunks ----
        f32x4 s[4];
#pragma unroll
        for (int tn = 0; tn < 4; ++tn) {
            const _Float16* kp = &Kl[(tn * 16 + col) * LDK + quad * 8];
            const f16x8 k0f = *(const f16x8*)kp;
            const f16x8 k1f = *(const f16x8*)(kp + 32);
            f32x4 acc = (f32x4){0.f, 0.f, 0.f, 0.f};
            acc = __builtin_amdgcn_mfma_f32_16x16x32_f16(qA0, k0f, acc, 0, 0, 0);
            acc = __builtin_amdgcn_mfma_f32_16x16x32_f16(qA1, k1f, acc, 0, 0, 0);
            s[tn] = acc;
        }

        // ---- causal mask (only the diagonal tile: k0 == q0) ----
        if (kt == nkt - 1) {
#pragma unroll
            for (int tn = 0; tn < 4; ++tn)
#pragma unroll
                for (int r = 0; r < 4; ++r) {
                    const int key = k0 + tn * 16 + col;
                    const int qq = q0 + w * 16 + quad * 4 + r;
                    if (key > qq) s[tn][r] = -1e30f;
                }
        }

        // ---- online softmax (rows = C-layout rows quad*4+r) ----
        float rm[4];
#pragma unroll
        for (int r = 0; r < 4; ++r)
            rm[r] = fmaxf(fmaxf(s[0][r], s[1][r]), fmaxf(s[2][r], s[3][r]));
#pragma unroll
        for (int st = 1; st < 16; st <<= 1)
#pragma unroll
            for (int r = 0; r < 4; ++r)
                rm[r] = fmaxf(rm[r], __shfl_xor(rm[r], st, 64));
        float corr[4];
#pragma unroll
        for (int r = 0; r < 4; ++r) {
            const float mn = fmaxf(m_[r], rm[r]);
            corr[r] = exp2f(m_[r] - mn);
            m_[r] = mn;
        }
        float rs[4] = {0.f, 0.f, 0.f, 0.f};
#pragma unroll
        for (int tn = 0; tn < 4; ++tn)
#pragma unroll
            for (int r = 0; r < 4; ++r) {
                const float p = exp2f(s[tn][r] - m_[r]);
                s[tn][r] = p;
                rs[r] += p;
            }
#pragma unroll
        for (int st = 1; st < 16; st <<= 1)
#pragma unroll
            for (int r = 0; r < 4; ++r)
                rs[r] += __shfl_xor(rs[r], st, 64);
#pragma unroll
        for (int r = 0; r < 4; ++r) l_[r] = l_[r] * corr[r] + rs[r];
#pragma unroll
        for (int tn = 0; tn < 4; ++tn)
#pragma unroll
            for (int r = 0; r < 4; ++r) oa[tn][r] *= corr[r];

        // ---- P -> LDS (A-operand layout source) ----
#pragma unroll
        for (int tn = 0; tn < 4; ++tn)
#pragma unroll
            for (int r = 0; r < 4; ++r)
                Pl[w][(quad * 4 + r) * LDP + tn * 16 + col] = (_Float16)s[tn][r];
        __syncthreads();

        // ---- O[16 q][64 d] += P @ V ----
        const _Float16* pp = &Pl[w][col * LDP + quad * 8];
        const f16x8 pA0 = *(const f16x8*)pp;         // keys 0..31
        const f16x8 pA1 = *(const f16x8*)(pp + 32);  // keys 32..63
#pragma unroll
        for (int tn = 0; tn < 4; ++tn) {
            const _Float16* vp = &Vl[(tn * 16 + col) * LDK + quad * 8];
            const f16x8 v0f = *(const f16x8*)vp;
            const f16x8 v1f = *(const f16x8*)(vp + 32);
            oa[tn] = __builtin_amdgcn_mfma_f32_16x16x32_f16(pA0, v0f, oa[tn], 0, 0, 0);
            oa[tn] = __builtin_amdgcn_mfma_f32_16x16x32_f16(pA1, v1f, oa[tn], 0, 0, 0);
        }
        __syncthreads();
    }

    // ---- normalize + write O (fp32, natural [b][t][h][d]) ----
    float inv[4];
#pragma unroll
    for (int r = 0; r < 4; ++r) inv[r] = 1.0f / l_[r];
#pragma unroll
    for (int tn = 0; tn < 4; ++tn)
#pragma unroll
        for (int r = 0; r < 4; ++r)
            o[((size_t)(b * T_ + q0 + w * 16 + quad * 4 + r) * H_ + h) * HD_ + tn * 16 + col] =
                oa[tn][r] * inv[r];
}

// ---------------------------------------------------------------------------
extern "C" void kernel_launch(void* const* d_in, const int* in_sizes, int n_in,
                              void* d_out, int out_size, void* d_ws, size_t ws_size,
                              hipStream_t stream) {
    const float* x  = (const float*)d_in[0];
    const float* wq = (const float*)d_in[1];
    const float* wk = (const float*)d_in[2];
    const float* wv = (const float*)d_in[3];
    const float* wo = (const float*)d_in[4];
    float* out = (float*)d_out;

    const size_t NE = (size_t)B_ * T_ * D_;  // 8,388,608
    float* qf = (float*)d_ws;
    float* kf = qf + NE;
    float* vf = kf + NE;
    _Float16* qh  = (_Float16*)(vf + NE);
    _Float16* kh  = qh + NE;
    _Float16* vth = kh + NE;

    dim3 gemm_grid(D_ / 64, (B_ * T_) / 64, 1);
    gemm_bt<<<gemm_grid, 256, 0, stream>>>(x, wq, qf);
    gemm_bt<<<gemm_grid, 256, 0, stream>>>(x, wk, kf);
    gemm_bt<<<gemm_grid, 256, 0, stream>>>(x, wv, vf);

    rmsrot<<<dim3(B_ * T_ * H_, 2), 64, 0, stream>>>(qf, kf, qh, kh);
    vtprep<<<dim3(T_ / 64, H_, B_), 256, 0, stream>>>(vf, vth);

    // flash writes O over qf (dead after rmsrot)
    flash_mfma<<<dim3(T_ / 64, H_, B_), 256, 0, stream>>>(qh, kh, vth, qf);

    gemm_bt<<<gemm_grid, 256, 0, stream>>>(qf, wo, out);
}

// Round 3
// 557.850 us; speedup vs baseline: 5.9867x; 3.1492x over previous
//
#include <hip/hip_runtime.h>
#include <hip/hip_bf16.h>
#include <math.h>

#define B_ 4
#define T_ 2048
#define D_ 1024
#define H_ 16
#define HD_ 64

typedef _Float16 f16x8 __attribute__((ext_vector_type(8)));
typedef _Float16 f16x4 __attribute__((ext_vector_type(4)));
typedef float f32x4 __attribute__((ext_vector_type(4)));

// async global->LDS, 16 B per lane, dest = wave-uniform base + lane*16
__device__ __forceinline__ void gload_lds16(const _Float16* g, _Float16* l) {
    __builtin_amdgcn_global_load_lds(
        (const __attribute__((address_space(1))) void*)g,
        (__attribute__((address_space(3))) void*)l,
        16, 0, 0);
}

// ---------------------------------------------------------------------------
// fp32 -> fp16 cast, 4 elems/thread
// ---------------------------------------------------------------------------
__global__ __launch_bounds__(256) void castf(const float* __restrict__ in,
                                             _Float16* __restrict__ out, int n4) {
    const int i = blockIdx.x * 256 + threadIdx.x;
    if (i < n4) {
        const float4 v = ((const float4*)in)[i];
        f16x4 h = {(_Float16)v.x, (_Float16)v.y, (_Float16)v.z, (_Float16)v.w};
        ((f16x4*)out)[i] = h;
    }
}

// ---------------------------------------------------------------------------
// MFMA GEMM: C[M,N] = A[M,K] @ W[N,K]^T, fp16 in, OutT out.
// M=8192 (or whatever grid.y*128), N=K=1024. 128x128 tile, BK=32,
// 256 thr = 4 waves in 2x2, each wave 64x64 via 4x4 mfma_f32_16x16x32_f16.
// Staging via global_load_lds width=16 (m97 ladder structure).
// blockIdx.z selects (W,C) pair for the fused q/k/v launch.
// ---------------------------------------------------------------------------
template <typename OutT>
__global__ __launch_bounds__(256) void gemm_f16_bt(const _Float16* __restrict__ A,
                                                   const _Float16* __restrict__ Wa,
                                                   const _Float16* __restrict__ Wb,
                                                   const _Float16* __restrict__ Wc,
                                                   OutT* __restrict__ Ca,
                                                   OutT* __restrict__ Cb,
                                                   OutT* __restrict__ Cc) {
    constexpr int K = D_, N = D_;
    const _Float16* W = (blockIdx.z == 0) ? Wa : (blockIdx.z == 1 ? Wb : Wc);
    OutT* C = (blockIdx.z == 0) ? Ca : (blockIdx.z == 1 ? Cb : Cc);
    __shared__ _Float16 As[128 * 32];
    __shared__ _Float16 Bs[128 * 32];
    const int tid = threadIdx.x;
    const int lane = tid & 63, w = tid >> 6;
    const int col = lane & 15, quad = lane >> 4;
    const int wm = w >> 1, wn = w & 1;
    const int row0 = blockIdx.y * 128, col0 = blockIdx.x * 128;
    const int sr = lane >> 2, sc = (lane & 3) * 8;  // staging: row-in-16, k-chunk

    f32x4 acc[4][4];
#pragma unroll
    for (int i = 0; i < 4; ++i)
#pragma unroll
        for (int j = 0; j < 4; ++j) acc[i][j] = (f32x4){0.f, 0.f, 0.f, 0.f};

    for (int kt = 0; kt < K / 32; ++kt) {
        const int k0 = kt * 32;
#pragma unroll
        for (int it = 0; it < 2; ++it) {
            const int rb = it * 64 + w * 16;  // wave-uniform
            gload_lds16(A + (size_t)(row0 + rb + sr) * K + k0 + sc, As + rb * 32);
            gload_lds16(W + (size_t)(col0 + rb + sr) * K + k0 + sc, Bs + rb * 32);
        }
        __syncthreads();
        f16x8 af[4], bf[4];
#pragma unroll
        for (int i = 0; i < 4; ++i) {
            af[i] = *(const f16x8*)&As[(wm * 64 + i * 16 + col) * 32 + quad * 8];
            bf[i] = *(const f16x8*)&Bs[(wn * 64 + i * 16 + col) * 32 + quad * 8];
        }
#pragma unroll
        for (int mi = 0; mi < 4; ++mi)
#pragma unroll
            for (int ni = 0; ni < 4; ++ni)
                acc[mi][ni] = __builtin_amdgcn_mfma_f32_16x16x32_f16(af[mi], bf[ni],
                                                                     acc[mi][ni], 0, 0, 0);
        __syncthreads();
    }
    // C/D layout: n = col, m = quad*4 + r (m89-verified)
#pragma unroll
    for (int mi = 0; mi < 4; ++mi)
#pragma unroll
        for (int ni = 0; ni < 4; ++ni)
#pragma unroll
            for (int r = 0; r < 4; ++r)
                C[(size_t)(row0 + wm * 64 + mi * 16 + quad * 4 + r) * N +
                  col0 + wn * 64 + ni * 16 + col] = (OutT)acc[mi][ni][r];
}

// ---------------------------------------------------------------------------
// Fused RMSNorm + rotary, fp16 in-place. Q pre-scaled by 0.125*log2(e).
// ---------------------------------------------------------------------------
__global__ __launch_bounds__(64) void rmsrot(_Float16* __restrict__ qh,
                                             _Float16* __restrict__ kh) {
    const int lane = threadIdx.x;
    const long long idx = blockIdx.x;          // (b*T + t)*H + h
    const int h = (int)(idx % H_);
    const long long bt = idx / H_;
    const int t = (int)(bt % T_);
    const long long off = bt * (long long)D_ + h * HD_ + lane;
    _Float16* p = (blockIdx.y == 0 ? qh : kh);
    float v = (float)p[off];
    float ss = v * v;
#pragma unroll
    for (int o = 32; o > 0; o >>= 1) ss += __shfl_xor(ss, o, 64);
    v *= rsqrtf(ss * (1.0f / 64.0f) + 1e-6f);
    const int j = lane & 31;
    const float f = (j < 16) ? exp2f(-10.0f * (float)j * (1.0f / 15.0f)) : 0.0f;
    const float theta = (float)t * f;
    float s, c;
    sincosf(theta, &s, &c);
    const float partner = __shfl_xor(v, 32, 64);
    float y = (lane < 32) ? fmaf(v, c, partner * s)
                          : fmaf(v, c, -partner * s);
    if (blockIdx.y == 0) y *= 0.18033688011112042f;  // 0.125*log2(e)
    p[off] = (_Float16)y;
}

// ---------------------------------------------------------------------------
// V transpose: fp16 V[b][t][h][d] -> fp16 Vt[b][h][d][T]
// ---------------------------------------------------------------------------
__global__ __launch_bounds__(256) void vtprep(const _Float16* __restrict__ vh,
                                              _Float16* __restrict__ vt) {
    __shared__ _Float16 Tl[64 * 80];
    const int tid = threadIdx.x;
    const int t0 = blockIdx.x * 64, h = blockIdx.y, b = blockIdx.z;
#pragma unroll
    for (int rep = 0; rep < 2; ++rep) {
        const int idx = rep * 256 + tid;  // 0..511
        const int r = idx >> 3;           // t row 0..63
        const int c = (idx & 7) * 8;      // d chunk
        const f16x8 v = *(const f16x8*)(vh + ((size_t)(b * T_ + t0 + r) * H_ + h) * HD_ + c);
#pragma unroll
        for (int jj = 0; jj < 8; ++jj) Tl[(c + jj) * 80 + r] = v[jj];
    }
    __syncthreads();
    const int d = tid >> 2, tc = (tid & 3) * 16;
    const uint4 a = *(const uint4*)&Tl[d * 80 + tc];
    const uint4 b4 = *(const uint4*)&Tl[d * 80 + tc + 8];
    _Float16* dst = vt + ((size_t)(b * H_ + h) * HD_ + d) * T_ + t0 + tc;
    *(uint4*)(dst) = a;
    *(uint4*)(dst + 8) = b4;
}

// ---------------------------------------------------------------------------
// MFMA flash attention (fp16 in, fp16 out). Unchanged structure from round 2.
// ---------------------------------------------------------------------------
#define LDK 88
#define LDP 88

__global__ __launch_bounds__(256) void flash_mfma(const _Float16* __restrict__ qh,
                                                  const _Float16* __restrict__ kh,
                                                  const _Float16* __restrict__ vt,
                                                  _Float16* __restrict__ o) {
    __shared__ _Float16 Kl[64 * LDK];
    __shared__ _Float16 Vl[64 * LDK];
    __shared__ _Float16 Pl[4][16 * LDP];
    const int tid = threadIdx.x;
    const int lane = tid & 63, w = tid >> 6;
    const int col = lane & 15, quad = lane >> 4;
    const int q0 = blockIdx.x * 64;
    const int h = blockIdx.y, b = blockIdx.z;

    const int tq = q0 + w * 16 + col;
    const _Float16* qp = qh + ((size_t)(b * T_ + tq) * H_ + h) * HD_ + quad * 8;
    const f16x8 qA0 = *(const f16x8*)(qp);
    const f16x8 qA1 = *(const f16x8*)(qp + 32);

    f32x4 oa[4];
#pragma unroll
    for (int i = 0; i < 4; ++i) oa[i] = (f32x4){0.f, 0.f, 0.f, 0.f};
    float m_[4] = {-1e30f, -1e30f, -1e30f, -1e30f};
    float l_[4] = {0.f, 0.f, 0.f, 0.f};

    const int nkt = blockIdx.x + 1;
    for (int kt = 0; kt < nkt; ++kt) {
        const int k0 = kt * 64;
#pragma unroll
        for (int rep = 0; rep < 2; ++rep) {
            const int idx = rep * 256 + tid;
            const int row = idx >> 3, ch = idx & 7;
            const uint4 kv = *(const uint4*)(kh + ((size_t)(b * T_ + k0 + row) * H_ + h) * HD_ + ch * 8);
            *(uint4*)&Kl[row * LDK + ch * 8] = kv;
            const uint4 vv = *(const uint4*)(vt + ((size_t)(b * H_ + h) * HD_ + row) * T_ + k0 + ch * 8);
            *(uint4*)&Vl[row * LDK + ch * 8] = vv;
        }
        __syncthreads();

        f32x4 s[4];
#pragma unroll
        for (int tn = 0; tn < 4; ++tn) {
            const _Float16* kp = &Kl[(tn * 16 + col) * LDK + quad * 8];
            const f16x8 k0f = *(const f16x8*)kp;
            const f16x8 k1f = *(const f16x8*)(kp + 32);
            f32x4 acc = (f32x4){0.f, 0.f, 0.f, 0.f};
            acc = __builtin_amdgcn_mfma_f32_16x16x32_f16(qA0, k0f, acc, 0, 0, 0);
            acc = __builtin_amdgcn_mfma_f32_16x16x32_f16(qA1, k1f, acc, 0, 0, 0);
            s[tn] = acc;
        }

        if (kt == nkt - 1) {
#pragma unroll
            for (int tn = 0; tn < 4; ++tn)
#pragma unroll
                for (int r = 0; r < 4; ++r) {
                    const int key = k0 + tn * 16 + col;
                    const int qq = q0 + w * 16 + quad * 4 + r;
                    if (key > qq) s[tn][r] = -1e30f;
                }
        }

        float rm[4];
#pragma unroll
        for (int r = 0; r < 4; ++r)
            rm[r] = fmaxf(fmaxf(s[0][r], s[1][r]), fmaxf(s[2][r], s[3][r]));
#pragma unroll
        for (int st = 1; st < 16; st <<= 1)
#pragma unroll
            for (int r = 0; r < 4; ++r)
                rm[r] = fmaxf(rm[r], __shfl_xor(rm[r], st, 64));
        float corr[4];
#pragma unroll
        for (int r = 0; r < 4; ++r) {
            const float mn = fmaxf(m_[r], rm[r]);
            corr[r] = exp2f(m_[r] - mn);
            m_[r] = mn;
        }
        float rs[4] = {0.f, 0.f, 0.f, 0.f};
#pragma unroll
        for (int tn = 0; tn < 4; ++tn)
#pragma unroll
            for (int r = 0; r < 4; ++r) {
                const float p = exp2f(s[tn][r] - m_[r]);
                s[tn][r] = p;
                rs[r] += p;
            }
#pragma unroll
        for (int st = 1; st < 16; st <<= 1)
#pragma unroll
            for (int r = 0; r < 4; ++r)
                rs[r] += __shfl_xor(rs[r], st, 64);
#pragma unroll
        for (int r = 0; r < 4; ++r) l_[r] = l_[r] * corr[r] + rs[r];
#pragma unroll
        for (int tn = 0; tn < 4; ++tn)
#pragma unroll
            for (int r = 0; r < 4; ++r) oa[tn][r] *= corr[r];

#pragma unroll
        for (int tn = 0; tn < 4; ++tn)
#pragma unroll
            for (int r = 0; r < 4; ++r)
                Pl[w][(quad * 4 + r) * LDP + tn * 16 + col] = (_Float16)s[tn][r];
        __syncthreads();

        const _Float16* pp = &Pl[w][col * LDP + quad * 8];
        const f16x8 pA0 = *(const f16x8*)pp;
        const f16x8 pA1 = *(const f16x8*)(pp + 32);
#pragma unroll
        for (int tn = 0; tn < 4; ++tn) {
            const _Float16* vp = &Vl[(tn * 16 + col) * LDK + quad * 8];
            const f16x8 v0f = *(const f16x8*)vp;
            const f16x8 v1f = *(const f16x8*)(vp + 32);
            oa[tn] = __builtin_amdgcn_mfma_f32_16x16x32_f16(pA0, v0f, oa[tn], 0, 0, 0);
            oa[tn] = __builtin_amdgcn_mfma_f32_16x16x32_f16(pA1, v1f, oa[tn], 0, 0, 0);
        }
        __syncthreads();
    }

    float inv[4];
#pragma unroll
    for (int r = 0; r < 4; ++r) inv[r] = 1.0f / l_[r];
#pragma unroll
    for (int tn = 0; tn < 4; ++tn)
#pragma unroll
        for (int r = 0; r < 4; ++r)
            o[((size_t)(b * T_ + q0 + w * 16 + quad * 4 + r) * H_ + h) * HD_ + tn * 16 + col] =
                (_Float16)(oa[tn][r] * inv[r]);
}

// ---------------------------------------------------------------------------
extern "C" void kernel_launch(void* const* d_in, const int* in_sizes, int n_in,
                              void* d_out, int out_size, void* d_ws, size_t ws_size,
                              hipStream_t stream) {
    const float* x  = (const float*)d_in[0];
    const float* wq = (const float*)d_in[1];
    const float* wk = (const float*)d_in[2];
    const float* wv = (const float*)d_in[3];
    const float* wo = (const float*)d_in[4];
    float* out = (float*)d_out;

    const size_t NE = (size_t)B_ * T_ * D_;   // 8,388,608
    const size_t WE = (size_t)D_ * D_;        // 1,048,576
    _Float16* xh  = (_Float16*)d_ws;
    _Float16* qh  = xh + NE;
    _Float16* kh  = qh + NE;
    _Float16* vh  = kh + NE;
    _Float16* vth = vh + NE;
    _Float16* wqh = vth + NE;
    _Float16* wkh = wqh + WE;
    _Float16* wvh = wkh + WE;
    _Float16* woh = wvh + WE;
    _Float16* oh  = vh;  // vh dead after vtprep; flash writes O here

    castf<<<NE / 1024, 256, 0, stream>>>(x, xh, (int)(NE / 4));
    castf<<<WE / 1024, 256, 0, stream>>>(wq, wqh, (int)(WE / 4));
    castf<<<WE / 1024, 256, 0, stream>>>(wk, wkh, (int)(WE / 4));
    castf<<<WE / 1024, 256, 0, stream>>>(wv, wvh, (int)(WE / 4));
    castf<<<WE / 1024, 256, 0, stream>>>(wo, woh, (int)(WE / 4));

    // fused q/k/v projection: grid z selects weight/output
    gemm_f16_bt<_Float16><<<dim3(D_ / 128, (B_ * T_) / 128, 3), 256, 0, stream>>>(
        xh, wqh, wkh, wvh, qh, kh, vh);

    rmsrot<<<dim3(B_ * T_ * H_, 2), 64, 0, stream>>>(qh, kh);
    vtprep<<<dim3(T_ / 64, H_, B_), 256, 0, stream>>>(vh, vth);

    flash_mfma<<<dim3(T_ / 64, H_, B_), 256, 0, stream>>>(qh, kh, vth, oh);

    gemm_f16_bt<float><<<dim3(D_ / 128, (B_ * T_) / 128, 1), 256, 0, stream>>>(
        oh, woh, woh, woh, out, out, out);
}

// Round 4
// 400.028 us; speedup vs baseline: 8.3486x; 1.3945x over previous
//
#include <hip/hip_runtime.h>
#include <hip/hip_bf16.h>
#include <math.h>

#define B_ 4
#define T_ 2048
#define D_ 1024
#define H_ 16
#define HD_ 64

typedef _Float16 f16x8 __attribute__((ext_vector_type(8)));
typedef _Float16 f16x4 __attribute__((ext_vector_type(4)));
typedef float f32x4 __attribute__((ext_vector_type(4)));

// async global->LDS, 16 B per lane, dest = wave-uniform base + lane*16
__device__ __forceinline__ void gload_lds16(const _Float16* g, _Float16* l) {
    __builtin_amdgcn_global_load_lds(
        (const __attribute__((address_space(1))) void*)g,
        (__attribute__((address_space(3))) void*)l,
        16, 0, 0);
}

// ---------------------------------------------------------------------------
// fp32 -> fp16 cast, 4 elems/thread
// ---------------------------------------------------------------------------
__global__ __launch_bounds__(256) void castf(const float* __restrict__ in,
                                             _Float16* __restrict__ out, int n4) {
    const int i = blockIdx.x * 256 + threadIdx.x;
    if (i < n4) {
        const float4 v = ((const float4*)in)[i];
        f16x4 h = {(_Float16)v.x, (_Float16)v.y, (_Float16)v.z, (_Float16)v.w};
        ((f16x4*)out)[i] = h;
    }
}

// ---------------------------------------------------------------------------
// MFMA GEMM: C[M,N] = A[M,K] @ W[N,K]^T, fp16 in, OutT out. (m97 structure)
// 128x128 tile, BK=32, 4 waves 2x2, global_load_lds width=16 staging.
// blockIdx.z selects (W,C) pair for the fused q/k/v launch.
// ---------------------------------------------------------------------------
template <typename OutT>
__global__ __launch_bounds__(256) void gemm_f16_bt(const _Float16* __restrict__ A,
                                                   const _Float16* __restrict__ Wa,
                                                   const _Float16* __restrict__ Wb,
                                                   const _Float16* __restrict__ Wc,
                                                   OutT* __restrict__ Ca,
                                                   OutT* __restrict__ Cb,
                                                   OutT* __restrict__ Cc) {
    constexpr int K = D_, N = D_;
    const _Float16* W = (blockIdx.z == 0) ? Wa : (blockIdx.z == 1 ? Wb : Wc);
    OutT* C = (blockIdx.z == 0) ? Ca : (blockIdx.z == 1 ? Cb : Cc);
    __shared__ _Float16 As[128 * 32];
    __shared__ _Float16 Bs[128 * 32];
    const int tid = threadIdx.x;
    const int lane = tid & 63, w = tid >> 6;
    const int col = lane & 15, quad = lane >> 4;
    const int wm = w >> 1, wn = w & 1;
    const int row0 = blockIdx.y * 128, col0 = blockIdx.x * 128;
    const int sr = lane >> 2, sc = (lane & 3) * 8;

    f32x4 acc[4][4];
#pragma unroll
    for (int i = 0; i < 4; ++i)
#pragma unroll
        for (int j = 0; j < 4; ++j) acc[i][j] = (f32x4){0.f, 0.f, 0.f, 0.f};

    for (int kt = 0; kt < K / 32; ++kt) {
        const int k0 = kt * 32;
#pragma unroll
        for (int it = 0; it < 2; ++it) {
            const int rb = it * 64 + w * 16;
            gload_lds16(A + (size_t)(row0 + rb + sr) * K + k0 + sc, As + rb * 32);
            gload_lds16(W + (size_t)(col0 + rb + sr) * K + k0 + sc, Bs + rb * 32);
        }
        __syncthreads();
        f16x8 af[4], bf[4];
#pragma unroll
        for (int i = 0; i < 4; ++i) {
            af[i] = *(const f16x8*)&As[(wm * 64 + i * 16 + col) * 32 + quad * 8];
            bf[i] = *(const f16x8*)&Bs[(wn * 64 + i * 16 + col) * 32 + quad * 8];
        }
#pragma unroll
        for (int mi = 0; mi < 4; ++mi)
#pragma unroll
            for (int ni = 0; ni < 4; ++ni)
                acc[mi][ni] = __builtin_amdgcn_mfma_f32_16x16x32_f16(af[mi], bf[ni],
                                                                     acc[mi][ni], 0, 0, 0);
        __syncthreads();
    }
#pragma unroll
    for (int mi = 0; mi < 4; ++mi)
#pragma unroll
        for (int ni = 0; ni < 4; ++ni)
#pragma unroll
            for (int r = 0; r < 4; ++r)
                C[(size_t)(row0 + wm * 64 + mi * 16 + quad * 4 + r) * N +
                  col0 + wn * 64 + ni * 16 + col] = (OutT)acc[mi][ni][r];
}

// ---------------------------------------------------------------------------
// Fused RMSNorm + rotary, fp16 in-place. 256 thr = 4 waves, 4 rows/block.
// Q pre-scaled by 0.125*log2(e) so flash uses exp2 with no extra scale.
// ---------------------------------------------------------------------------
__global__ __launch_bounds__(256) void rmsrot(_Float16* __restrict__ qh,
                                              _Float16* __restrict__ kh) {
    const int lane = threadIdx.x & 63;
    const int sub = threadIdx.x >> 6;
    const long long idx = (long long)blockIdx.x * 4 + sub;  // (b*T + t)*H + h
    const int h = (int)(idx % H_);
    const long long bt = idx / H_;
    const int t = (int)(bt % T_);
    const long long off = bt * (long long)D_ + h * HD_ + lane;
    _Float16* p = (blockIdx.y == 0 ? qh : kh);
    float v = (float)p[off];
    float ss = v * v;
#pragma unroll
    for (int o = 32; o > 0; o >>= 1) ss += __shfl_xor(ss, o, 64);
    v *= rsqrtf(ss * (1.0f / 64.0f) + 1e-6f);
    const int j = lane & 31;
    const float f = (j < 16) ? exp2f(-10.0f * (float)j * (1.0f / 15.0f)) : 0.0f;
    const float theta = (float)t * f;
    float s, c;
    sincosf(theta, &s, &c);
    const float partner = __shfl_xor(v, 32, 64);
    float y = (lane < 32) ? fmaf(v, c, partner * s)
                          : fmaf(v, c, -partner * s);
    if (blockIdx.y == 0) y *= 0.18033688011112042f;  // 0.125*log2(e)
    p[off] = (_Float16)y;
}

// ---------------------------------------------------------------------------
// V transpose: fp16 V[b][t][h][d] -> fp16 Vt[b][h][d][T]
// ---------------------------------------------------------------------------
__global__ __launch_bounds__(256) void vtprep(const _Float16* __restrict__ vh,
                                              _Float16* __restrict__ vt) {
    __shared__ _Float16 Tl[64 * 80];
    const int tid = threadIdx.x;
    const int t0 = blockIdx.x * 64, h = blockIdx.y, b = blockIdx.z;
#pragma unroll
    for (int rep = 0; rep < 2; ++rep) {
        const int idx = rep * 256 + tid;
        const int r = idx >> 3;
        const int c = (idx & 7) * 8;
        const f16x8 v = *(const f16x8*)(vh + ((size_t)(b * T_ + t0 + r) * H_ + h) * HD_ + c);
#pragma unroll
        for (int jj = 0; jj < 8; ++jj) Tl[(c + jj) * 80 + r] = v[jj];
    }
    __syncthreads();
    const int d = tid >> 2, tc = (tid & 3) * 16;
    const uint4 a = *(const uint4*)&Tl[d * 80 + tc];
    const uint4 b4 = *(const uint4*)&Tl[d * 80 + tc + 8];
    _Float16* dst = vt + ((size_t)(b * H_ + h) * HD_ + d) * T_ + t0 + tc;
    *(uint4*)(dst) = a;
    *(uint4*)(dst + 8) = b4;
}

// ---------------------------------------------------------------------------
// MFMA flash attention (fp16 in, fp16 out).
// Diagonal-paired blocks: block x handles q-tiles {x, 31-x} -> uniform 33
// K-tiles/block, grid (16,16,4)=1024 blocks.
// Bounded-score softmax: after rmsnorm |score| <= 8 (Cauchy-Schwarz), so in
// log2 domain s <= 11.54, p = exp2(s) <= 2980 fits fp16; no running max, no
// rescale, l accumulated in-lane and butterflied once per q-tile.
// 2 barriers per K-tile (P round-trip is wave-private -> no barrier).
// ---------------------------------------------------------------------------
#define LDK 88
#define LDP 88

__global__ __launch_bounds__(256) void flash_mfma(const _Float16* __restrict__ qh,
                                                  const _Float16* __restrict__ kh,
                                                  const _Float16* __restrict__ vt,
                                                  _Float16* __restrict__ o) {
    __shared__ _Float16 Kl[64 * LDK];
    __shared__ _Float16 Vl[64 * LDK];
    __shared__ _Float16 Pl[4][16 * LDP];
    const int tid = threadIdx.x;
    const int lane = tid & 63, w = tid >> 6;
    const int col = lane & 15, quad = lane >> 4;
    const int h = blockIdx.y, b = blockIdx.z;

    for (int phase = 0; phase < 2; ++phase) {
        const int qt = (phase == 0) ? (int)blockIdx.x : (31 - (int)blockIdx.x);
        const int q0 = qt * 64;

        const int tq = q0 + w * 16 + col;
        const _Float16* qp = qh + ((size_t)(b * T_ + tq) * H_ + h) * HD_ + quad * 8;
        const f16x8 qA0 = *(const f16x8*)(qp);
        const f16x8 qA1 = *(const f16x8*)(qp + 32);

        f32x4 oa[4];
#pragma unroll
        for (int i = 0; i < 4; ++i) oa[i] = (f32x4){0.f, 0.f, 0.f, 0.f};
        float l_[4] = {0.f, 0.f, 0.f, 0.f};

        const int nkt = qt + 1;
        for (int kt = 0; kt < nkt; ++kt) {
            const int k0 = kt * 64;
#pragma unroll
            for (int rep = 0; rep < 2; ++rep) {
                const int idx = rep * 256 + tid;
                const int row = idx >> 3, ch = idx & 7;
                const uint4 kv = *(const uint4*)(kh + ((size_t)(b * T_ + k0 + row) * H_ + h) * HD_ + ch * 8);
                *(uint4*)&Kl[row * LDK + ch * 8] = kv;
                const uint4 vv = *(const uint4*)(vt + ((size_t)(b * H_ + h) * HD_ + row) * T_ + k0 + ch * 8);
                *(uint4*)&Vl[row * LDK + ch * 8] = vv;
            }
            __syncthreads();

            // ---- S[16 q][64 key] = Q @ K^T ----
            f32x4 s[4];
#pragma unroll
            for (int tn = 0; tn < 4; ++tn) {
                const _Float16* kp = &Kl[(tn * 16 + col) * LDK + quad * 8];
                const f16x8 k0f = *(const f16x8*)kp;
                const f16x8 k1f = *(const f16x8*)(kp + 32);
                f32x4 acc = (f32x4){0.f, 0.f, 0.f, 0.f};
                acc = __builtin_amdgcn_mfma_f32_16x16x32_f16(qA0, k0f, acc, 0, 0, 0);
                acc = __builtin_amdgcn_mfma_f32_16x16x32_f16(qA1, k1f, acc, 0, 0, 0);
                s[tn] = acc;
            }

            // ---- causal mask on the diagonal tile ----
            if (kt == qt) {
#pragma unroll
                for (int tn = 0; tn < 4; ++tn)
#pragma unroll
                    for (int r = 0; r < 4; ++r) {
                        const int key = k0 + tn * 16 + col;
                        const int qq = q0 + w * 16 + quad * 4 + r;
                        if (key > qq) s[tn][r] = -1e30f;
                    }
            }

            // ---- p = exp2(s); accumulate l in-lane; P -> LDS (A layout) ----
#pragma unroll
            for (int tn = 0; tn < 4; ++tn)
#pragma unroll
                for (int r = 0; r < 4; ++r) {
                    const float p = exp2f(s[tn][r]);
                    l_[r] += p;
                    Pl[w][(quad * 4 + r) * LDP + tn * 16 + col] = (_Float16)p;
                }

            // ---- O += P @ V  (Pl[w] wave-private: no barrier needed) ----
            const _Float16* pp = &Pl[w][col * LDP + quad * 8];
            const f16x8 pA0 = *(const f16x8*)pp;
            const f16x8 pA1 = *(const f16x8*)(pp + 32);
#pragma unroll
            for (int tn = 0; tn < 4; ++tn) {
                const _Float16* vp = &Vl[(tn * 16 + col) * LDK + quad * 8];
                const f16x8 v0f = *(const f16x8*)vp;
                const f16x8 v1f = *(const f16x8*)(vp + 32);
                oa[tn] = __builtin_amdgcn_mfma_f32_16x16x32_f16(pA0, v0f, oa[tn], 0, 0, 0);
                oa[tn] = __builtin_amdgcn_mfma_f32_16x16x32_f16(pA1, v1f, oa[tn], 0, 0, 0);
            }
            __syncthreads();
        }

        // ---- reduce l across the 16 col lanes (once per q-tile) ----
#pragma unroll
        for (int st = 1; st < 16; st <<= 1)
#pragma unroll
            for (int r = 0; r < 4; ++r)
                l_[r] += __shfl_xor(l_[r], st, 64);

        float inv[4];
#pragma unroll
        for (int r = 0; r < 4; ++r) inv[r] = 1.0f / l_[r];
#pragma unroll
        for (int tn = 0; tn < 4; ++tn)
#pragma unroll
            for (int r = 0; r < 4; ++r)
                o[((size_t)(b * T_ + q0 + w * 16 + quad * 4 + r) * H_ + h) * HD_ + tn * 16 + col] =
                    (_Float16)(oa[tn][r] * inv[r]);
        // last inner-loop barrier already separates this phase's LDS reads
        // from the next phase's staging writes
    }
}

// ---------------------------------------------------------------------------
extern "C" void kernel_launch(void* const* d_in, const int* in_sizes, int n_in,
                              void* d_out, int out_size, void* d_ws, size_t ws_size,
                              hipStream_t stream) {
    const float* x  = (const float*)d_in[0];
    const float* wq = (const float*)d_in[1];
    const float* wk = (const float*)d_in[2];
    const float* wv = (const float*)d_in[3];
    const float* wo = (const float*)d_in[4];
    float* out = (float*)d_out;

    const size_t NE = (size_t)B_ * T_ * D_;   // 8,388,608
    const size_t WE = (size_t)D_ * D_;        // 1,048,576
    _Float16* xh  = (_Float16*)d_ws;
    _Float16* qh  = xh + NE;
    _Float16* kh  = qh + NE;
    _Float16* vh  = kh + NE;
    _Float16* vth = vh + NE;
    _Float16* wqh = vth + NE;
    _Float16* wkh = wqh + WE;
    _Float16* wvh = wkh + WE;
    _Float16* woh = wvh + WE;
    _Float16* oh  = vh;  // vh dead after vtprep; flash writes O here

    castf<<<NE / 1024, 256, 0, stream>>>(x, xh, (int)(NE / 4));
    castf<<<WE / 1024, 256, 0, stream>>>(wq, wqh, (int)(WE / 4));
    castf<<<WE / 1024, 256, 0, stream>>>(wk, wkh, (int)(WE / 4));
    castf<<<WE / 1024, 256, 0, stream>>>(wv, wvh, (int)(WE / 4));
    castf<<<WE / 1024, 256, 0, stream>>>(wo, woh, (int)(WE / 4));

    gemm_f16_bt<_Float16><<<dim3(D_ / 128, (B_ * T_) / 128, 3), 256, 0, stream>>>(
        xh, wqh, wkh, wvh, qh, kh, vh);

    rmsrot<<<dim3(B_ * T_ * H_ / 4, 2), 256, 0, stream>>>(qh, kh);
    vtprep<<<dim3(T_ / 64, H_, B_), 256, 0, stream>>>(vh, vth);

    flash_mfma<<<dim3(16, H_, B_), 256, 0, stream>>>(qh, kh, vth, oh);

    gemm_f16_bt<float><<<dim3(D_ / 128, (B_ * T_) / 128, 1), 256, 0, stream>>>(
        oh, woh, woh, woh, out, out, out);
}

// Round 5
// 302.258 us; speedup vs baseline: 11.0491x; 1.3235x over previous
//
#include <hip/hip_runtime.h>
#include <hip/hip_bf16.h>
#include <math.h>

#define B_ 4
#define T_ 2048
#define D_ 1024
#define H_ 16
#define HD_ 64

typedef _Float16 f16x8 __attribute__((ext_vector_type(8)));
typedef _Float16 f16x4 __attribute__((ext_vector_type(4)));
typedef float f32x4 __attribute__((ext_vector_type(4)));

// async global->LDS, 16 B per lane, dest = wave-uniform base + lane*16
__device__ __forceinline__ void gload_lds16(const _Float16* g, _Float16* l) {
    __builtin_amdgcn_global_load_lds(
        (const __attribute__((address_space(1))) void*)g,
        (__attribute__((address_space(3))) void*)l,
        16, 0, 0);
}

// ---------------------------------------------------------------------------
// fp32 -> fp16 cast, 4 elems/thread
// ---------------------------------------------------------------------------
__global__ __launch_bounds__(256) void castf(const float* __restrict__ in,
                                             _Float16* __restrict__ out, int n4) {
    const int i = blockIdx.x * 256 + threadIdx.x;
    if (i < n4) {
        const float4 v = ((const float4*)in)[i];
        f16x4 h = {(_Float16)v.x, (_Float16)v.y, (_Float16)v.z, (_Float16)v.w};
        ((f16x4*)out)[i] = h;
    }
}

// ---------------------------------------------------------------------------
// Fused QKV GEMM + rmsnorm/rotary epilogue.
// C[M,N] = A[M,K] @ W[N,K]^T, 128x128 tile, BK=32, 4 waves 2x2,
// global_load_lds width=16 staging (m97 structure).
// z=0: rms+rotary+0.125*log2e scale -> qh (f16, natural layout)
// z=1: rms+rotary -> kh
// z=2: plain -> vt transposed [b][h][d][T]
// ---------------------------------------------------------------------------
__global__ __launch_bounds__(256) void gemm_qkv(const _Float16* __restrict__ A,
                                                const _Float16* __restrict__ Wq,
                                                const _Float16* __restrict__ Wk,
                                                const _Float16* __restrict__ Wv,
                                                _Float16* __restrict__ qh,
                                                _Float16* __restrict__ kh,
                                                _Float16* __restrict__ vt) {
    constexpr int K = D_;
    const int z = blockIdx.z;
    const _Float16* W = (z == 0) ? Wq : (z == 1 ? Wk : Wv);
    __shared__ _Float16 As[128 * 32];
    __shared__ _Float16 Bs[128 * 32];
    const int tid = threadIdx.x;
    const int lane = tid & 63, w = tid >> 6;
    const int col = lane & 15, quad = lane >> 4;
    const int wm = w >> 1, wn = w & 1;
    const int row0 = blockIdx.y * 128, col0 = blockIdx.x * 128;
    const int sr = lane >> 2, sc = (lane & 3) * 8;

    f32x4 acc[4][4];
#pragma unroll
    for (int i = 0; i < 4; ++i)
#pragma unroll
        for (int j = 0; j < 4; ++j) acc[i][j] = (f32x4){0.f, 0.f, 0.f, 0.f};

    for (int kt = 0; kt < K / 32; ++kt) {
        const int k0 = kt * 32;
#pragma unroll
        for (int it = 0; it < 2; ++it) {
            const int rb = it * 64 + w * 16;
            gload_lds16(A + (size_t)(row0 + rb + sr) * K + k0 + sc, As + rb * 32);
            gload_lds16(W + (size_t)(col0 + rb + sr) * K + k0 + sc, Bs + rb * 32);
        }
        __syncthreads();
        f16x8 af[4], bf[4];
#pragma unroll
        for (int i = 0; i < 4; ++i) {
            af[i] = *(const f16x8*)&As[(wm * 64 + i * 16 + col) * 32 + quad * 8];
            bf[i] = *(const f16x8*)&Bs[(wn * 64 + i * 16 + col) * 32 + quad * 8];
        }
#pragma unroll
        for (int mi = 0; mi < 4; ++mi)
#pragma unroll
            for (int ni = 0; ni < 4; ++ni)
                acc[mi][ni] = __builtin_amdgcn_mfma_f32_16x16x32_f16(af[mi], bf[ni],
                                                                     acc[mi][ni], 0, 0, 0);
        __syncthreads();
    }

    if (z < 2) {
        // ---- rmsnorm over the 64-col head this wave owns + rotary ----
        _Float16* C = (z == 0) ? qh : kh;
        const float qscale = (z == 0) ? 0.18033688011112042f : 1.0f;  // 0.125*log2(e)
        const float fr = exp2f(-10.0f * (float)col * (1.0f / 15.0f));  // freq j=col
#pragma unroll
        for (int mi = 0; mi < 4; ++mi) {
            float ssq[4];
#pragma unroll
            for (int r = 0; r < 4; ++r) {
                float t = 0.f;
#pragma unroll
                for (int ni = 0; ni < 4; ++ni) t += acc[mi][ni][r] * acc[mi][ni][r];
                ssq[r] = t;
            }
#pragma unroll
            for (int st = 1; st < 16; st <<= 1)
#pragma unroll
                for (int r = 0; r < 4; ++r) ssq[r] += __shfl_xor(ssq[r], st, 64);
            const int rowb = row0 + wm * 64 + mi * 16 + quad * 4;
#pragma unroll
            for (int r = 0; r < 4; ++r) {
                const float scl = rsqrtf(ssq[r] * (1.0f / 64.0f) + 1e-6f) * qscale;
                const int t = (rowb + r) & (T_ - 1);
                float s, c;
                sincosf((float)t * fr, &s, &c);
                const float x0 = acc[mi][0][r] * scl;
                const float x1 = acc[mi][1][r] * scl;
                const float x2 = acc[mi][2][r] * scl;
                const float x3 = acc[mi][3][r] * scl;
                const float y0 = fmaf(x0, c, x2 * s);
                const float y2 = fmaf(x2, c, -x0 * s);
                const size_t base = (size_t)(rowb + r) * D_ + col0 + wn * 64 + col;
                C[base + 0]  = (_Float16)y0;
                C[base + 16] = (_Float16)x1;
                C[base + 32] = (_Float16)y2;
                C[base + 48] = (_Float16)x3;
            }
        }
    } else {
        // ---- V: write transposed vt[b][h][d][T] ----
        const int hh = blockIdx.x * 2 + wn;
#pragma unroll
        for (int mi = 0; mi < 4; ++mi) {
            const int row = row0 + wm * 64 + mi * 16 + quad * 4;
            const int bb = row >> 11;
            const int t0m = row & (T_ - 1);
#pragma unroll
            for (int ni = 0; ni < 4; ++ni) {
                const int d = ni * 16 + col;
                f16x4 pk = {(_Float16)acc[mi][ni][0], (_Float16)acc[mi][ni][1],
                            (_Float16)acc[mi][ni][2], (_Float16)acc[mi][ni][3]};
                *(f16x4*)&vt[((size_t)(bb * H_ + hh) * HD_ + d) * T_ + t0m] = pk;
            }
        }
    }
}

// ---------------------------------------------------------------------------
// WO GEMM: out[M,N] = A[M,K] @ W[N,K]^T, fp16 in, fp32 out. m97 structure.
// ---------------------------------------------------------------------------
__global__ __launch_bounds__(256) void gemm_wo(const _Float16* __restrict__ A,
                                               const _Float16* __restrict__ W,
                                               float* __restrict__ C) {
    constexpr int K = D_, N = D_;
    __shared__ _Float16 As[128 * 32];
    __shared__ _Float16 Bs[128 * 32];
    const int tid = threadIdx.x;
    const int lane = tid & 63, w = tid >> 6;
    const int col = lane & 15, quad = lane >> 4;
    const int wm = w >> 1, wn = w & 1;
    const int row0 = blockIdx.y * 128, col0 = blockIdx.x * 128;
    const int sr = lane >> 2, sc = (lane & 3) * 8;

    f32x4 acc[4][4];
#pragma unroll
    for (int i = 0; i < 4; ++i)
#pragma unroll
        for (int j = 0; j < 4; ++j) acc[i][j] = (f32x4){0.f, 0.f, 0.f, 0.f};

    for (int kt = 0; kt < K / 32; ++kt) {
        const int k0 = kt * 32;
#pragma unroll
        for (int it = 0; it < 2; ++it) {
            const int rb = it * 64 + w * 16;
            gload_lds16(A + (size_t)(row0 + rb + sr) * K + k0 + sc, As + rb * 32);
            gload_lds16(W + (size_t)(col0 + rb + sr) * K + k0 + sc, Bs + rb * 32);
        }
        __syncthreads();
        f16x8 af[4], bf[4];
#pragma unroll
        for (int i = 0; i < 4; ++i) {
            af[i] = *(const f16x8*)&As[(wm * 64 + i * 16 + col) * 32 + quad * 8];
            bf[i] = *(const f16x8*)&Bs[(wn * 64 + i * 16 + col) * 32 + quad * 8];
        }
#pragma unroll
        for (int mi = 0; mi < 4; ++mi)
#pragma unroll
            for (int ni = 0; ni < 4; ++ni)
                acc[mi][ni] = __builtin_amdgcn_mfma_f32_16x16x32_f16(af[mi], bf[ni],
                                                                     acc[mi][ni], 0, 0, 0);
        __syncthreads();
    }
#pragma unroll
    for (int mi = 0; mi < 4; ++mi)
#pragma unroll
        for (int ni = 0; ni < 4; ++ni)
#pragma unroll
            for (int r = 0; r < 4; ++r)
                C[(size_t)(row0 + wm * 64 + mi * 16 + quad * 4 + r) * N +
                  col0 + wn * 64 + ni * 16 + col] = acc[mi][ni][r];
}

// ---------------------------------------------------------------------------
// MFMA flash attention (fp16 in/out). Block: 64 q, 4 waves x 16 q.
// Diagonal pairing: block x does q-tiles {x, 31-x} -> uniform 33 K-tiles.
// S^T formulation: S^T = K @ Q^T (A=K, B=Q) so C-layout rows = keys ->
// P transpose to LDS is 4 packed ds_write_b64 per tile (not 16 b16).
// K/V staged via global_load_lds into unpadded [64][64] with XOR chunk
// swizzle (chunk ^= row&7) applied on the global source side.
// Bounded-score softmax (|s|<=11.54 in log2 domain after rmsnorm): no
// running max; l is one scalar per lane (q=col), butterflied over quads.
// ---------------------------------------------------------------------------
#define LDP 88

__global__ __launch_bounds__(256) void flash_mfma(const _Float16* __restrict__ qh,
                                                  const _Float16* __restrict__ kh,
                                                  const _Float16* __restrict__ vt,
                                                  _Float16* __restrict__ o) {
    __shared__ _Float16 Kl[64 * 64];
    __shared__ _Float16 Vl[64 * 64];
    __shared__ _Float16 Pl[4][16 * LDP];
    const int tid = threadIdx.x;
    const int lane = tid & 63, w = tid >> 6;
    const int col = lane & 15, quad = lane >> 4;
    const int h = blockIdx.y, b = blockIdx.z;
    // staging: lane -> row offset (lane>>3), swizzled chunk
    const int srow = lane >> 3;
    const int schunk = (lane & 7) ^ srow;
    const int sw = col & 7;  // read-side swizzle key (row&7 = col&7 for our rows)

    for (int phase = 0; phase < 2; ++phase) {
        const int qt = (phase == 0) ? (int)blockIdx.x : (31 - (int)blockIdx.x);
        const int q0 = qt * 64;

        // Q as B-operand: lane holds Q[q=q0+16w+col][d = quad*8+j (+32)]
        const int tq = q0 + w * 16 + col;
        const _Float16* qp = qh + ((size_t)(b * T_ + tq) * H_ + h) * HD_ + quad * 8;
        const f16x8 qB0 = *(const f16x8*)(qp);
        const f16x8 qB1 = *(const f16x8*)(qp + 32);

        f32x4 oa[4];
#pragma unroll
        for (int i = 0; i < 4; ++i) oa[i] = (f32x4){0.f, 0.f, 0.f, 0.f};
        float l_ = 0.f;  // per-lane partial denom for q = col

        const int nkt = qt + 1;
        for (int kt = 0; kt < nkt; ++kt) {
            const int k0 = kt * 64;
            // ---- stage K[key][d] and Vt[d][key], swizzled, async ----
#pragma unroll
            for (int i = 0; i < 2; ++i) {
                const int r = w * 16 + i * 8 + srow;
                gload_lds16(kh + ((size_t)(b * T_ + k0 + r) * H_ + h) * HD_ + schunk * 8,
                            Kl + (w * 16 + i * 8) * 64);
                gload_lds16(vt + ((size_t)(b * H_ + h) * HD_ + r) * T_ + k0 + schunk * 8,
                            Vl + (w * 16 + i * 8) * 64);
            }
            __syncthreads();

            // ---- S^T[key][q]: A = K rows, B = Q (in regs) ----
            f32x4 s[4];
#pragma unroll
            for (int tn = 0; tn < 4; ++tn) {
                const _Float16* kp = &Kl[(tn * 16 + col) * 64];
                const f16x8 kA0 = *(const f16x8*)(kp + ((quad ^ sw) << 3));
                const f16x8 kA1 = *(const f16x8*)(kp + (((quad | 4) ^ sw) << 3));
                f32x4 a = (f32x4){0.f, 0.f, 0.f, 0.f};
                a = __builtin_amdgcn_mfma_f32_16x16x32_f16(kA0, qB0, a, 0, 0, 0);
                a = __builtin_amdgcn_mfma_f32_16x16x32_f16(kA1, qB1, a, 0, 0, 0);
                s[tn] = a;
            }

            // ---- causal mask on diagonal tile: key > q -> -inf ----
            if (kt == qt) {
                const int qq = q0 + w * 16 + col;
#pragma unroll
                for (int tn = 0; tn < 4; ++tn)
#pragma unroll
                    for (int r = 0; r < 4; ++r) {
                        const int key = k0 + tn * 16 + quad * 4 + r;
                        if (key > qq) s[tn][r] = -1e30f;
                    }
            }

            // ---- p = exp2(s); l accumulate; packed P store (4x b64) ----
#pragma unroll
            for (int tn = 0; tn < 4; ++tn) {
                f16x4 pk;
#pragma unroll
                for (int r = 0; r < 4; ++r) {
                    const float p = exp2f(s[tn][r]);
                    l_ += p;
                    pk[r] = (_Float16)p;
                }
                *(f16x4*)&Pl[w][col * LDP + tn * 16 + quad * 4] = pk;
            }

            // ---- O[q][d] += P @ V (Pl[w] wave-private, no barrier) ----
            const f16x8 pA0 = *(const f16x8*)&Pl[w][col * LDP + quad * 8];
            const f16x8 pA1 = *(const f16x8*)&Pl[w][col * LDP + quad * 8 + 32];
#pragma unroll
            for (int tn = 0; tn < 4; ++tn) {
                const _Float16* vp = &Vl[(tn * 16 + col) * 64];
                const f16x8 vB0 = *(const f16x8*)(vp + ((quad ^ sw) << 3));
                const f16x8 vB1 = *(const f16x8*)(vp + (((quad | 4) ^ sw) << 3));
                oa[tn] = __builtin_amdgcn_mfma_f32_16x16x32_f16(pA0, vB0, oa[tn], 0, 0, 0);
                oa[tn] = __builtin_amdgcn_mfma_f32_16x16x32_f16(pA1, vB1, oa[tn], 0, 0, 0);
            }
            __syncthreads();
        }

        // ---- finish l (sum quads), redistribute to O rows, write ----
        l_ += __shfl_xor(l_, 16, 64);
        l_ += __shfl_xor(l_, 32, 64);
        const float linv = 1.0f / l_;
        float inv[4];
#pragma unroll
        for (int r = 0; r < 4; ++r) inv[r] = __shfl(linv, quad * 4 + r, 64);
#pragma unroll
        for (int tn = 0; tn < 4; ++tn)
#pragma unroll
            for (int r = 0; r < 4; ++r)
                o[((size_t)(b * T_ + q0 + w * 16 + quad * 4 + r) * H_ + h) * HD_ + tn * 16 + col] =
                    (_Float16)(oa[tn][r] * inv[r]);
    }
}

// ---------------------------------------------------------------------------
extern "C" void kernel_launch(void* const* d_in, const int* in_sizes, int n_in,
                              void* d_out, int out_size, void* d_ws, size_t ws_size,
                              hipStream_t stream) {
    const float* x  = (const float*)d_in[0];
    const float* wq = (const float*)d_in[1];
    const float* wk = (const float*)d_in[2];
    const float* wv = (const float*)d_in[3];
    const float* wo = (const float*)d_in[4];
    float* out = (float*)d_out;

    const size_t NE = (size_t)B_ * T_ * D_;   // 8,388,608
    const size_t WE = (size_t)D_ * D_;        // 1,048,576
    _Float16* xh  = (_Float16*)d_ws;
    _Float16* qh  = xh + NE;
    _Float16* kh  = qh + NE;
    _Float16* vth = kh + NE;
    _Float16* oh  = vth + NE;
    _Float16* wqh = oh + NE;
    _Float16* wkh = wqh + WE;
    _Float16* wvh = wkh + WE;
    _Float16* woh = wvh + WE;

    castf<<<NE / 1024, 256, 0, stream>>>(x, xh, (int)(NE / 4));
    castf<<<WE / 1024, 256, 0, stream>>>(wq, wqh, (int)(WE / 4));
    castf<<<WE / 1024, 256, 0, stream>>>(wk, wkh, (int)(WE / 4));
    castf<<<WE / 1024, 256, 0, stream>>>(wv, wvh, (int)(WE / 4));
    castf<<<WE / 1024, 256, 0, stream>>>(wo, woh, (int)(WE / 4));

    // fused q/k/v projection + rmsnorm/rotary/transpose epilogues
    gemm_qkv<<<dim3(D_ / 128, (B_ * T_) / 128, 3), 256, 0, stream>>>(
        xh, wqh, wkh, wvh, qh, kh, vth);

    flash_mfma<<<dim3(16, H_, B_), 256, 0, stream>>>(qh, kh, vth, oh);

    gemm_wo<<<dim3(D_ / 128, (B_ * T_) / 128, 1), 256, 0, stream>>>(oh, woh, out);
}

// Round 6
// 279.447 us; speedup vs baseline: 11.9510x; 1.0816x over previous
//
#include <hip/hip_runtime.h>
#include <hip/hip_bf16.h>
#include <math.h>

#define B_ 4
#define T_ 2048
#define D_ 1024
#define H_ 16
#define HD_ 64

typedef _Float16 f16x8 __attribute__((ext_vector_type(8)));
typedef _Float16 f16x4 __attribute__((ext_vector_type(4)));
typedef float f32x4 __attribute__((ext_vector_type(4)));

// async global->LDS, 16 B per lane, dest = wave-uniform base + lane*16
__device__ __forceinline__ void gload_lds16(const _Float16* g, _Float16* l) {
    __builtin_amdgcn_global_load_lds(
        (const __attribute__((address_space(1))) void*)g,
        (__attribute__((address_space(3))) void*)l,
        16, 0, 0);
}

// ---------------------------------------------------------------------------
// fp32 -> fp16 cast, 4 elems/thread
// ---------------------------------------------------------------------------
__global__ __launch_bounds__(256) void castf(const float* __restrict__ in,
                                             _Float16* __restrict__ out, int n4) {
    const int i = blockIdx.x * 256 + threadIdx.x;
    if (i < n4) {
        const float4 v = ((const float4*)in)[i];
        f16x4 h = {(_Float16)v.x, (_Float16)v.y, (_Float16)v.z, (_Float16)v.w};
        ((f16x4*)out)[i] = h;
    }
}

// fused 4-weight cast: grid.z selects which weight
__global__ __launch_bounds__(256) void castw(const float* __restrict__ a,
                                             const float* __restrict__ b,
                                             const float* __restrict__ c,
                                             const float* __restrict__ d,
                                             _Float16* __restrict__ oa,
                                             _Float16* __restrict__ ob,
                                             _Float16* __restrict__ oc,
                                             _Float16* __restrict__ od) {
    const int z = blockIdx.z;
    const float* in = (z == 0) ? a : (z == 1 ? b : (z == 2 ? c : d));
    _Float16* out = (z == 0) ? oa : (z == 1 ? ob : (z == 2 ? oc : od));
    const int i = blockIdx.x * 256 + threadIdx.x;
    const float4 v = ((const float4*)in)[i];
    f16x4 h = {(_Float16)v.x, (_Float16)v.y, (_Float16)v.z, (_Float16)v.w};
    ((f16x4*)out)[i] = h;
}

// ---------------------------------------------------------------------------
// Fused QKV GEMM + rmsnorm/rotary epilogue (m97 structure).
// z=0: rms+rotary+0.125*log2e -> qh ; z=1: rms+rotary -> kh ;
// z=2: plain -> vt transposed [b][h][d][T]
// ---------------------------------------------------------------------------
__global__ __launch_bounds__(256) void gemm_qkv(const _Float16* __restrict__ A,
                                                const _Float16* __restrict__ Wq,
                                                const _Float16* __restrict__ Wk,
                                                const _Float16* __restrict__ Wv,
                                                _Float16* __restrict__ qh,
                                                _Float16* __restrict__ kh,
                                                _Float16* __restrict__ vt) {
    constexpr int K = D_;
    const int z = blockIdx.z;
    const _Float16* W = (z == 0) ? Wq : (z == 1 ? Wk : Wv);
    __shared__ _Float16 As[128 * 32];
    __shared__ _Float16 Bs[128 * 32];
    const int tid = threadIdx.x;
    const int lane = tid & 63, w = tid >> 6;
    const int col = lane & 15, quad = lane >> 4;
    const int wm = w >> 1, wn = w & 1;
    const int row0 = blockIdx.y * 128, col0 = blockIdx.x * 128;
    const int sr = lane >> 2, sc = (lane & 3) * 8;

    f32x4 acc[4][4];
#pragma unroll
    for (int i = 0; i < 4; ++i)
#pragma unroll
        for (int j = 0; j < 4; ++j) acc[i][j] = (f32x4){0.f, 0.f, 0.f, 0.f};

    for (int kt = 0; kt < K / 32; ++kt) {
        const int k0 = kt * 32;
#pragma unroll
        for (int it = 0; it < 2; ++it) {
            const int rb = it * 64 + w * 16;
            gload_lds16(A + (size_t)(row0 + rb + sr) * K + k0 + sc, As + rb * 32);
            gload_lds16(W + (size_t)(col0 + rb + sr) * K + k0 + sc, Bs + rb * 32);
        }
        __syncthreads();
        f16x8 af[4], bf[4];
#pragma unroll
        for (int i = 0; i < 4; ++i) {
            af[i] = *(const f16x8*)&As[(wm * 64 + i * 16 + col) * 32 + quad * 8];
            bf[i] = *(const f16x8*)&Bs[(wn * 64 + i * 16 + col) * 32 + quad * 8];
        }
#pragma unroll
        for (int mi = 0; mi < 4; ++mi)
#pragma unroll
            for (int ni = 0; ni < 4; ++ni)
                acc[mi][ni] = __builtin_amdgcn_mfma_f32_16x16x32_f16(af[mi], bf[ni],
                                                                     acc[mi][ni], 0, 0, 0);
        __syncthreads();
    }

    if (z < 2) {
        _Float16* C = (z == 0) ? qh : kh;
        const float qscale = (z == 0) ? 0.18033688011112042f : 1.0f;  // 0.125*log2(e)
        const float fr = exp2f(-10.0f * (float)col * (1.0f / 15.0f));
#pragma unroll
        for (int mi = 0; mi < 4; ++mi) {
            float ssq[4];
#pragma unroll
            for (int r = 0; r < 4; ++r) {
                float t = 0.f;
#pragma unroll
                for (int ni = 0; ni < 4; ++ni) t += acc[mi][ni][r] * acc[mi][ni][r];
                ssq[r] = t;
            }
#pragma unroll
            for (int st = 1; st < 16; st <<= 1)
#pragma unroll
                for (int r = 0; r < 4; ++r) ssq[r] += __shfl_xor(ssq[r], st, 64);
            const int rowb = row0 + wm * 64 + mi * 16 + quad * 4;
#pragma unroll
            for (int r = 0; r < 4; ++r) {
                const float scl = rsqrtf(ssq[r] * (1.0f / 64.0f) + 1e-6f) * qscale;
                const int t = (rowb + r) & (T_ - 1);
                float s, c;
                sincosf((float)t * fr, &s, &c);
                const float x0 = acc[mi][0][r] * scl;
                const float x1 = acc[mi][1][r] * scl;
                const float x2 = acc[mi][2][r] * scl;
                const float x3 = acc[mi][3][r] * scl;
                const float y0 = fmaf(x0, c, x2 * s);
                const float y2 = fmaf(x2, c, -x0 * s);
                const size_t base = (size_t)(rowb + r) * D_ + col0 + wn * 64 + col;
                C[base + 0]  = (_Float16)y0;
                C[base + 16] = (_Float16)x1;
                C[base + 32] = (_Float16)y2;
                C[base + 48] = (_Float16)x3;
            }
        }
    } else {
        const int hh = blockIdx.x * 2 + wn;
#pragma unroll
        for (int mi = 0; mi < 4; ++mi) {
            const int row = row0 + wm * 64 + mi * 16 + quad * 4;
            const int bb = row >> 11;
            const int t0m = row & (T_ - 1);
#pragma unroll
            for (int ni = 0; ni < 4; ++ni) {
                const int d = ni * 16 + col;
                f16x4 pk = {(_Float16)acc[mi][ni][0], (_Float16)acc[mi][ni][1],
                            (_Float16)acc[mi][ni][2], (_Float16)acc[mi][ni][3]};
                *(f16x4*)&vt[((size_t)(bb * H_ + hh) * HD_ + d) * T_ + t0m] = pk;
            }
        }
    }
}

// ---------------------------------------------------------------------------
// WO GEMM: out[M,N] = A[M,K] @ W[N,K]^T, fp16 in, fp32 out. m97 structure.
// ---------------------------------------------------------------------------
__global__ __launch_bounds__(256) void gemm_wo(const _Float16* __restrict__ A,
                                               const _Float16* __restrict__ W,
                                               float* __restrict__ C) {
    constexpr int K = D_, N = D_;
    __shared__ _Float16 As[128 * 32];
    __shared__ _Float16 Bs[128 * 32];
    const int tid = threadIdx.x;
    const int lane = tid & 63, w = tid >> 6;
    const int col = lane & 15, quad = lane >> 4;
    const int wm = w >> 1, wn = w & 1;
    const int row0 = blockIdx.y * 128, col0 = blockIdx.x * 128;
    const int sr = lane >> 2, sc = (lane & 3) * 8;

    f32x4 acc[4][4];
#pragma unroll
    for (int i = 0; i < 4; ++i)
#pragma unroll
        for (int j = 0; j < 4; ++j) acc[i][j] = (f32x4){0.f, 0.f, 0.f, 0.f};

    for (int kt = 0; kt < K / 32; ++kt) {
        const int k0 = kt * 32;
#pragma unroll
        for (int it = 0; it < 2; ++it) {
            const int rb = it * 64 + w * 16;
            gload_lds16(A + (size_t)(row0 + rb + sr) * K + k0 + sc, As + rb * 32);
            gload_lds16(W + (size_t)(col0 + rb + sr) * K + k0 + sc, Bs + rb * 32);
        }
        __syncthreads();
        f16x8 af[4], bf[4];
#pragma unroll
        for (int i = 0; i < 4; ++i) {
            af[i] = *(const f16x8*)&As[(wm * 64 + i * 16 + col) * 32 + quad * 8];
            bf[i] = *(const f16x8*)&Bs[(wn * 64 + i * 16 + col) * 32 + quad * 8];
        }
#pragma unroll
        for (int mi = 0; mi < 4; ++mi)
#pragma unroll
            for (int ni = 0; ni < 4; ++ni)
                acc[mi][ni] = __builtin_amdgcn_mfma_f32_16x16x32_f16(af[mi], bf[ni],
                                                                     acc[mi][ni], 0, 0, 0);
        __syncthreads();
    }
#pragma unroll
    for (int mi = 0; mi < 4; ++mi)
#pragma unroll
        for (int ni = 0; ni < 4; ++ni)
#pragma unroll
            for (int r = 0; r < 4; ++r)
                C[(size_t)(row0 + wm * 64 + mi * 16 + quad * 4 + r) * N +
                  col0 + wn * 64 + ni * 16 + col] = acc[mi][ni][r];
}

// ---------------------------------------------------------------------------
// MFMA flash attention (fp16 in/out). 512 thr = 8 waves, 128 q per block,
// wave w owns q rows [q0+16w, q0+16w+16). K-tiles of 64 keys.
// XCD-aware grid: (64 bh, 8 pair) -> all blocks of one (b,h) have linear
// id = bh (mod 8) -> same XCD -> K/V cached once per XCD (4 MB/L2).
// Diagonal pairing over 16 q-tiles: block y does {y, 15-y} -> uniform 34
// K-tiles. S^T form (A=K, B=Q): C rows = keys -> packed b64 P-stores.
// K/V staged by global_load_lds, XOR-chunk swizzle on the global side.
// Bounded-score softmax (|s|<=11.54 log2-domain after rmsnorm): no max
// pass; l per-lane + 2 butterflies per q-tile.
// ---------------------------------------------------------------------------
#define LDP 88

__global__ __launch_bounds__(512) void flash_mfma(const _Float16* __restrict__ qh,
                                                  const _Float16* __restrict__ kh,
                                                  const _Float16* __restrict__ vt,
                                                  _Float16* __restrict__ o) {
    __shared__ _Float16 Kl[64 * 64];
    __shared__ _Float16 Vl[64 * 64];
    __shared__ _Float16 Pl[8][16 * LDP];
    const int tid = threadIdx.x;
    const int lane = tid & 63, w = tid >> 6;           // w in [0,8)
    const int col = lane & 15, quad = lane >> 4;
    const int bh = blockIdx.x, b = bh >> 4, h = bh & 15;
    const int srow = lane >> 3;                        // row-in-8 for staging
    const int schunk = (lane & 7) ^ srow;              // global-side swizzle
    const int sw = col & 7;                            // read-side swizzle key

    for (int phase = 0; phase < 2; ++phase) {
        const int qt = (phase == 0) ? (int)blockIdx.y : (15 - (int)blockIdx.y);
        const int q0 = qt * 128;

        // Q as B-operand: lane holds Q[q=q0+16w+col][d = quad*8+j (+32)]
        const int tq = q0 + w * 16 + col;
        const _Float16* qp = qh + ((size_t)(b * T_ + tq) * H_ + h) * HD_ + quad * 8;
        const f16x8 qB0 = *(const f16x8*)(qp);
        const f16x8 qB1 = *(const f16x8*)(qp + 32);

        f32x4 oa[4];
#pragma unroll
        for (int i = 0; i < 4; ++i) oa[i] = (f32x4){0.f, 0.f, 0.f, 0.f};
        float l_ = 0.f;  // per-lane partial denom for q = col

        const int nkt = 2 * qt + 2;
        for (int kt = 0; kt < nkt; ++kt) {
            const int k0 = kt * 64;
            // ---- stage K[key][d], Vt[d][key]: 512 thr x 16 B = full tile ----
            {
                const int r = w * 8 + srow;
                gload_lds16(kh + ((size_t)(b * T_ + k0 + r) * H_ + h) * HD_ + schunk * 8,
                            Kl + (w * 8) * 64);
                gload_lds16(vt + ((size_t)(b * H_ + h) * HD_ + r) * T_ + k0 + schunk * 8,
                            Vl + (w * 8) * 64);
            }
            __syncthreads();

            // ---- S^T[key][q]: A = K rows, B = Q (in regs) ----
            f32x4 s[4];
#pragma unroll
            for (int tn = 0; tn < 4; ++tn) {
                const _Float16* kp = &Kl[(tn * 16 + col) * 64];
                const f16x8 kA0 = *(const f16x8*)(kp + ((quad ^ sw) << 3));
                const f16x8 kA1 = *(const f16x8*)(kp + (((quad | 4) ^ sw) << 3));
                f32x4 a = (f32x4){0.f, 0.f, 0.f, 0.f};
                a = __builtin_amdgcn_mfma_f32_16x16x32_f16(kA0, qB0, a, 0, 0, 0);
                a = __builtin_amdgcn_mfma_f32_16x16x32_f16(kA1, qB1, a, 0, 0, 0);
                s[tn] = a;
            }

            // ---- causal mask: any key in tile beyond this wave's q rows ----
            if (k0 + 63 > q0 + w * 16) {
                const int qq = q0 + w * 16 + col;
#pragma unroll
                for (int tn = 0; tn < 4; ++tn)
#pragma unroll
                    for (int r = 0; r < 4; ++r) {
                        const int key = k0 + tn * 16 + quad * 4 + r;
                        if (key > qq) s[tn][r] = -1e30f;
                    }
            }

            // ---- p = exp2(s); l accumulate; packed P store (4x b64) ----
#pragma unroll
            for (int tn = 0; tn < 4; ++tn) {
                f16x4 pk;
#pragma unroll
                for (int r = 0; r < 4; ++r) {
                    const float p = exp2f(s[tn][r]);
                    l_ += p;
                    pk[r] = (_Float16)p;
                }
                *(f16x4*)&Pl[w][col * LDP + tn * 16 + quad * 4] = pk;
            }

            // ---- O[q][d] += P @ V (Pl[w] wave-private, no barrier) ----
            const f16x8 pA0 = *(const f16x8*)&Pl[w][col * LDP + quad * 8];
            const f16x8 pA1 = *(const f16x8*)&Pl[w][col * LDP + quad * 8 + 32];
#pragma unroll
            for (int tn = 0; tn < 4; ++tn) {
                const _Float16* vp = &Vl[(tn * 16 + col) * 64];
                const f16x8 vB0 = *(const f16x8*)(vp + ((quad ^ sw) << 3));
                const f16x8 vB1 = *(const f16x8*)(vp + (((quad | 4) ^ sw) << 3));
                oa[tn] = __builtin_amdgcn_mfma_f32_16x16x32_f16(pA0, vB0, oa[tn], 0, 0, 0);
                oa[tn] = __builtin_amdgcn_mfma_f32_16x16x32_f16(pA1, vB1, oa[tn], 0, 0, 0);
            }
            __syncthreads();
        }

        // ---- finish l (sum quads), redistribute to O rows, write ----
        l_ += __shfl_xor(l_, 16, 64);
        l_ += __shfl_xor(l_, 32, 64);
        const float linv = 1.0f / l_;
        float inv[4];
#pragma unroll
        for (int r = 0; r < 4; ++r) inv[r] = __shfl(linv, quad * 4 + r, 64);
#pragma unroll
        for (int tn = 0; tn < 4; ++tn)
#pragma unroll
            for (int r = 0; r < 4; ++r)
                o[((size_t)(b * T_ + q0 + w * 16 + quad * 4 + r) * H_ + h) * HD_ + tn * 16 + col] =
                    (_Float16)(oa[tn][r] * inv[r]);
    }
}

// ---------------------------------------------------------------------------
extern "C" void kernel_launch(void* const* d_in, const int* in_sizes, int n_in,
                              void* d_out, int out_size, void* d_ws, size_t ws_size,
                              hipStream_t stream) {
    const float* x  = (const float*)d_in[0];
    const float* wq = (const float*)d_in[1];
    const float* wk = (const float*)d_in[2];
    const float* wv = (const float*)d_in[3];
    const float* wo = (const float*)d_in[4];
    float* out = (float*)d_out;

    const size_t NE = (size_t)B_ * T_ * D_;   // 8,388,608
    const size_t WE = (size_t)D_ * D_;        // 1,048,576
    _Float16* xh  = (_Float16*)d_ws;
    _Float16* qh  = xh + NE;
    _Float16* kh  = qh + NE;
    _Float16* vth = kh + NE;
    _Float16* oh  = vth + NE;
    _Float16* wqh = oh + NE;
    _Float16* wkh = wqh + WE;
    _Float16* wvh = wkh + WE;
    _Float16* woh = wvh + WE;

    castf<<<NE / 1024, 256, 0, stream>>>(x, xh, (int)(NE / 4));
    castw<<<dim3(WE / 1024, 1, 4), 256, 0, stream>>>(wq, wk, wv, wo,
                                                     wqh, wkh, wvh, woh);

    gemm_qkv<<<dim3(D_ / 128, (B_ * T_) / 128, 3), 256, 0, stream>>>(
        xh, wqh, wkh, wvh, qh, kh, vth);

    flash_mfma<<<dim3(B_ * H_, 8, 1), 512, 0, stream>>>(qh, kh, vth, oh);

    gemm_wo<<<dim3(D_ / 128, (B_ * T_) / 128, 1), 256, 0, stream>>>(oh, woh, out);
}